// Round 4
// baseline (164.131 us; speedup 1.0000x reference)
//
#include <hip/hip_runtime.h>

// ---------------- problem constants ----------------
#define Bb 10
#define Hh 50
#define Ww 101
#define Kk 4096
#define SLICE (Hh*Ww)             // 5050
#define NBLK 160                  // grid size; <= 256 CUs so all blocks co-resident

// conv1: IC=3 OC=32 k7 s2 p3 : [10,3,50,101] -> [10,32,25,51]; pool1 k3 s2 -> [10,32,12,25]
// conv2: IC=32 OC=64 k5 s1 p2 -> [10,64,12,25]; pool2 k2 s2 -> [10,64,6,12]
// conv3: IC=64 OC=128 k3 s1 p1 -> [10,128,6,12]; pool3 k2 s2 -> [10,128,3,6]

// ---------------- grid-wide barrier (counters zeroed by memsetAsync each launch) ----------------
__device__ __forceinline__ void gridbar(unsigned* ctr, int slot) {
    __syncthreads();
    if (threadIdx.x == 0) {
        __threadfence();                              // release: flush prior writes device-wide
        unsigned prev = atomicAdd(&ctr[slot * 16], 1u);
        if (prev + 1u < (unsigned)NBLK) {
            while (__hip_atomic_load(&ctr[slot * 16], __ATOMIC_ACQUIRE,
                                     __HIP_MEMORY_SCOPE_AGENT) < (unsigned)NBLK) {
                __builtin_amdgcn_s_sleep(2);
            }
        } else {
            __hip_atomic_load(&ctr[slot * 16], __ATOMIC_ACQUIRE, __HIP_MEMORY_SCOPE_AGENT);
        }
    }
    __syncthreads();
}

__global__ __launch_bounds__(256) void mega_kernel(
        const int* __restrict__ x,
        const float* __restrict__ w1, const float* __restrict__ b1,
        const float* __restrict__ w2, const float* __restrict__ b2,
        const float* __restrict__ w3, const float* __restrict__ b3,
        const float* __restrict__ wl1, const float* __restrict__ bl1,
        const float* __restrict__ wl2, const float* __restrict__ bl2,
        float* __restrict__ grid, float* __restrict__ p1,
        float* __restrict__ p2, float* __restrict__ p3,
        unsigned* __restrict__ barctr, float* __restrict__ out) {
    __shared__ __align__(16) char smem_raw[59392];    // max phase need: conv2 stage 32*16*29*4
    float* smf = (float*)smem_raw;
    int* lastK = (int*)smem_raw;
    int blk = blockIdx.x;
    int tid = threadIdx.x;

    // ---------- P0: scatter + 3x3 max-dilate + decode -> grid ----------
    if (blk < 30) {
        int bc = blk;
        for (int i = tid; i < SLICE; i += 256) lastK[i] = -1;
        __syncthreads();
        const int2* xp = (const int2*)(x + bc * Kk * 2);   // (col,row)
        for (int k = tid; k < Kk + 1; k += 256) {
            int col, row;
            if (k == 0) { col = 50; row = 48; }
            else { int2 p = xp[k - 1]; col = p.x; row = p.y; }
            atomicMax(&lastK[row * Ww + col], k);
        }
        __syncthreads();
        float* g = grid + bc * SLICE;
        for (int i = tid; i < SLICE; i += 256) {
            int r = i / Ww, c = i % Ww;
            int m = -1;
            #pragma unroll
            for (int dr = -1; dr <= 1; ++dr) {
                int rr = r + dr;
                if (rr < 0 || rr >= Hh) continue;
                #pragma unroll
                for (int dc = -1; dc <= 1; ++dc) {
                    int cc = c + dc;
                    if (cc < 0 || cc >= Ww) continue;
                    m = max(m, lastK[rr * Ww + cc]);
                }
            }
            g[i] = (m < 0) ? 0.0f : ((lastK[i] == m) ? 1.0f : 0.5f);
        }
    }
    gridbar(barctr, 0);

    // ---------- P1: conv1 + pool1 (task = (b, ocpair), 160 tasks) ----------
    {
        int b = blk / 16, ocpair = blk % 16;
        int oc0 = ocpair * 2;
        float* ctile = smf + 6144;            // [2][25][52] after lds_in [56*109]
        bool active = tid < 250;              // (oh 25) x (owt 10), 6-wide w/ benign overlap
        int oh = tid / 10, owt = tid % 10;
        int ow0 = owt * 5;
        float acc0[6] = {0,0,0,0,0,0}, acc1[6] = {0,0,0,0,0,0};
        for (int ic = 0; ic < 3; ++ic) {
            for (int i = tid; i < 56 * 109; i += 256) {
                int r = i / 109, c = i % 109;
                int gr = r - 3, gc = c - 3;
                float v = 0.f;
                if (gr >= 0 && gr < Hh && gc >= 0 && gc < Ww)
                    v = grid[((b * 3 + ic) * Hh + gr) * Ww + gc];
                smf[i] = v;
            }
            __syncthreads();
            if (active) {
                const float* wp0 = w1 + (oc0 * 3 + ic) * 49;
                const float* wp1 = w1 + ((oc0 + 1) * 3 + ic) * 49;
                #pragma unroll
                for (int kh = 0; kh < 7; ++kh) {
                    const float* lr = smf + (2 * oh + kh) * 109 + 2 * ow0;
                    float s[17];
                    #pragma unroll
                    for (int k = 0; k < 17; ++k) s[k] = lr[k];
                    float wa[7], wb_[7];
                    #pragma unroll
                    for (int k = 0; k < 7; ++k) { wa[k] = wp0[kh * 7 + k]; wb_[k] = wp1[kh * 7 + k]; }
                    #pragma unroll
                    for (int kw = 0; kw < 7; ++kw)
                        #pragma unroll
                        for (int j = 0; j < 6; ++j) {
                            acc0[j] += s[2 * j + kw] * wa[kw];
                            acc1[j] += s[2 * j + kw] * wb_[kw];
                        }
                }
            }
            __syncthreads();
        }
        if (active) {
            float bia0 = b1[oc0], bia1 = b1[oc0 + 1];
            #pragma unroll
            for (int j = 0; j < 6; ++j) {
                int ow = ow0 + j;   // <= 50 always; overlapping threads write identical values
                ctile[(0 * 25 + oh) * 52 + ow] = fmaxf(acc0[j] + bia0, 0.f);
                ctile[(1 * 25 + oh) * 52 + ow] = fmaxf(acc1[j] + bia1, 0.f);
            }
        }
        __syncthreads();
        for (int pu = tid; pu < 600; pu += 256) {    // 2 oc x 12 x 25
            int oc = pu / 300, rem = pu % 300;
            int ph = rem / 25, pw = rem % 25;
            const float* cp = ctile + (oc * 25 + 2 * ph) * 52 + 2 * pw;
            float m = -INFINITY;
            #pragma unroll
            for (int r = 0; r < 3; ++r)
                #pragma unroll
                for (int c = 0; c < 3; ++c)
                    m = fmaxf(m, cp[r * 52 + c]);
            p1[((b * 32 + oc0 + oc) * 12 + ph) * 25 + pw] = m;
        }
    }
    gridbar(barctr, 1);

    // ---------- P2: conv2 + pool2 (16 blocks per b, full input staged) ----------
    {
        int b = blk / 16, blk16 = blk % 16;
        for (int i = tid; i < 32 * 16 * 29; i += 256) {
            int ic = i / 464, rem = i % 464;
            int r = rem / 29, c = rem % 29;
            int gr = r - 2, gc = c - 2;
            float v = 0.f;
            if (gr >= 0 && gr < 12 && gc >= 0 && gc < 25)
                v = p1[((b * 32 + ic) * 12 + gr) * 25 + gc];
            smf[i] = v;
        }
        __syncthreads();
        for (int t = tid; t < 288; t += 256) {       // 4608/16 outputs per block
            int u = blk16 * 288 + t;
            int pw = u % 12, ph = (u / 12) % 6, oc = u / 72;
            float acc[2][2] = {{0.f, 0.f}, {0.f, 0.f}};
            const float* wbase = w2 + oc * 32 * 25;
            const float* lbase = smf + (2 * ph) * 29 + 2 * pw;
            for (int ic = 0; ic < 32; ++ic) {
                float inr[6][6];
                const float* lp = lbase + ic * 464;
                #pragma unroll
                for (int r = 0; r < 6; ++r)
                    #pragma unroll
                    for (int c = 0; c < 6; ++c)
                        inr[r][c] = lp[r * 29 + c];
                const float* wp = wbase + ic * 25;
                float wr[25];
                #pragma unroll
                for (int k = 0; k < 25; ++k) wr[k] = wp[k];
                #pragma unroll
                for (int kh = 0; kh < 5; ++kh)
                    #pragma unroll
                    for (int kw = 0; kw < 5; ++kw)
                        #pragma unroll
                        for (int dy = 0; dy < 2; ++dy)
                            #pragma unroll
                            for (int dx = 0; dx < 2; ++dx)
                                acc[dy][dx] += inr[dy + kh][dx + kw] * wr[kh * 5 + kw];
            }
            float bia = b2[oc];
            float m = fmaxf(fmaxf(fmaxf(acc[0][0], acc[0][1]), fmaxf(acc[1][0], acc[1][1])) + bia, 0.f);
            p2[((b * 64 + oc) * 6 + ph) * 12 + pw] = m;
        }
    }
    gridbar(barctr, 2);

    // ---------- P3: conv3 + pool3 (16 blocks per b) ----------
    {
        int b = blk / 16, blk16 = blk % 16;
        for (int i = tid; i < 64 * 8 * 14; i += 256) {
            int ic = i / 112, rem = i % 112;
            int r = rem / 14, c = rem % 14;
            int gr = r - 1, gc = c - 1;
            float v = 0.f;
            if (gr >= 0 && gr < 6 && gc >= 0 && gc < 12)
                v = p2[((b * 64 + ic) * 6 + gr) * 12 + gc];
            smf[i] = v;
        }
        __syncthreads();
        if (tid < 144) {                              // 2304/16 outputs per block
            int u = blk16 * 144 + tid;
            int pw = u % 6, ph = (u / 6) % 3, oc = u / 18;
            float acc[2][2] = {{0.f, 0.f}, {0.f, 0.f}};
            const float* wbase = w3 + oc * 64 * 9;
            const float* lbase = smf + (2 * ph) * 14 + 2 * pw;
            for (int ic = 0; ic < 64; ++ic) {
                float inr[4][4];
                const float* lp = lbase + ic * 112;
                #pragma unroll
                for (int r = 0; r < 4; ++r)
                    #pragma unroll
                    for (int c = 0; c < 4; ++c)
                        inr[r][c] = lp[r * 14 + c];
                const float* wp = wbase + ic * 9;
                float wr[9];
                #pragma unroll
                for (int k = 0; k < 9; ++k) wr[k] = wp[k];
                #pragma unroll
                for (int kh = 0; kh < 3; ++kh)
                    #pragma unroll
                    for (int kw = 0; kw < 3; ++kw)
                        #pragma unroll
                        for (int dy = 0; dy < 2; ++dy)
                            #pragma unroll
                            for (int dx = 0; dx < 2; ++dx)
                                acc[dy][dx] += inr[dy + kh][dx + kw] * wr[kh * 3 + kw];
            }
            float bia = b3[oc];
            float m = fmaxf(fmaxf(fmaxf(acc[0][0], acc[0][1]), fmaxf(acc[1][0], acc[1][1])) + bia, 0.f);
            p3[((b * 128 + oc) * 3 + ph) * 6 + pw] = m;
        }
    }
    gridbar(barctr, 3);

    // ---------- P4: head (blocks 0..9) ----------
    if (blk < 10) {
        int b = blk;
        float* feat = smf;        // 128
        float* h2 = smf + 128;    // 128
        int c = tid;
        if (c < 128) {
            const float* p = p3 + (b * 128 + c) * 18;
            float s = 0.0f;
            #pragma unroll
            for (int i = 0; i < 18; ++i) s += p[i];
            feat[c] = s * (1.0f / 18.0f);
        }
        __syncthreads();
        if (c < 128) {
            float a = bl1[c];
            const float4* wr = (const float4*)(wl1 + c * 128);
            #pragma unroll 8
            for (int k4 = 0; k4 < 32; ++k4) {
                float4 w = wr[k4];
                a += feat[4 * k4] * w.x + feat[4 * k4 + 1] * w.y
                   + feat[4 * k4 + 2] * w.z + feat[4 * k4 + 3] * w.w;
            }
            h2[c] = fmaxf(a, 0.0f);
        }
        __syncthreads();
        if (c < 5) {
            float a2 = bl2[c];
            const float4* wr2 = (const float4*)(wl2 + c * 128);
            #pragma unroll 8
            for (int k4 = 0; k4 < 32; ++k4) {
                float4 w = wr2[k4];
                a2 += h2[4 * k4] * w.x + h2[4 * k4 + 1] * w.y
                    + h2[4 * k4 + 2] * w.z + h2[4 * k4 + 3] * w.w;
            }
            out[b * 5 + c] = a2;
        }
    }
}

// ---------------- launch ----------------
extern "C" void kernel_launch(void* const* d_in, const int* in_sizes, int n_in,
                              void* d_out, int out_size, void* d_ws, size_t ws_size,
                              hipStream_t stream) {
    const int*   x   = (const int*)d_in[0];
    const float* w1  = (const float*)d_in[1];
    const float* b1  = (const float*)d_in[2];
    const float* w2  = (const float*)d_in[3];
    const float* b2  = (const float*)d_in[4];
    const float* w3  = (const float*)d_in[5];
    const float* b3  = (const float*)d_in[6];
    const float* wl1 = (const float*)d_in[7];
    const float* bl1 = (const float*)d_in[8];
    const float* wl2 = (const float*)d_in[9];
    const float* bl2 = (const float*)d_in[10];
    float* out = (float*)d_out;

    // workspace layout:
    //   grid @ 0        : 606000 B
    //   p1   @ 606000   : 384000 B
    //   p2   @ 990000   : 184320 B
    //   p3   @ 1174320  : 92160 B
    //   bar  @ 1280000  : 512 B  (zeroed every launch)
    char* ws = (char*)d_ws;
    float*    grid   = (float*)ws;
    float*    p1     = (float*)(ws + 606000);
    float*    p2     = (float*)(ws + 990000);
    float*    p3     = (float*)(ws + 1174320);
    unsigned* barctr = (unsigned*)(ws + 1280000);

    hipMemsetAsync(barctr, 0, 512, stream);
    mega_kernel<<<NBLK, 256, 0, stream>>>(x, w1, b1, w2, b2, w3, b3,
                                          wl1, bl1, wl2, bl2,
                                          grid, p1, p2, p3, barctr, out);
}

// Round 7
// 103.891 us; speedup vs baseline: 1.5798x; 1.5798x over previous
//
#include <hip/hip_runtime.h>

// ---------------- problem constants ----------------
#define Bb 10
#define Hh 50
#define Ww 101
#define Kk 4096
#define SLICE (Hh*Ww)   // 5050

// conv1: IC=3 OC=32 k7 s2 p3 -> [10,32,25,51]; pool1 k3 s2 -> [10,32,12,25]
// conv2: IC=32 OC=64 k5 s1 p2 -> [10,64,12,25]; pool2 k2 s2 -> [10,64,6,12]
// conv3: IC=64 OC=128 k3 s1 p1 -> [10,128,6,12]; pool3 k2 s2 -> [10,128,3,6]

// ================= K_A: scatter + dilate + conv1 + pool1 =================
// 160 blocks (b, ocpair) x 384 threads. Each block recomputes its batch's 3
// grid channels from x in LDS (redundant across the 16 ocpair blocks of a b,
// but fully parallel -> no sync needed). grid never touches global memory.
__global__ __launch_bounds__(384) void scatter_conv1p1_kernel(
        const int* __restrict__ x, const float* __restrict__ w1,
        const float* __restrict__ b1, float* __restrict__ p1,
        unsigned* __restrict__ cnt) {
    __shared__ int lastK[SLICE];          // 20200 B
    __shared__ float pad[56 * 109];       // 24416 B  (zero-padded grid channel)
    __shared__ float ctile[2 * 25 * 52];  // 10400 B  (conv out, pre-pool)
    int blk = blockIdx.x;
    int b = blk / 16, ocpair = blk % 16;
    int oc0 = ocpair * 2;
    int tid = threadIdx.x;
    if (blk < Bb && tid == 0)             // zero head counters for K_C (coherent store)
        __hip_atomic_store(&cnt[blk], 0u, __ATOMIC_RELEASE, __HIP_MEMORY_SCOPE_AGENT);

    bool active = tid < 325;              // (oh 25) x (owt 13)
    int oh = tid / 13, owt = tid % 13;
    int ow0 = owt * 4;
    float acc0[4] = {0.f, 0.f, 0.f, 0.f};
    float acc1[4] = {0.f, 0.f, 0.f, 0.f};

    for (int ic = 0; ic < 3; ++ic) {
        // -- scatter: lastK[cell] = max point index centered at cell --
        for (int i = tid; i < SLICE; i += 384) lastK[i] = -1;
        __syncthreads();
        const int2* xp = (const int2*)(x + (b * 3 + ic) * Kk * 2);   // (col,row)
        for (int k = tid; k < Kk + 1; k += 384) {
            int col, row;
            if (k == 0) { col = 50; row = 48; }        // prepended base fill
            else { int2 p = xp[k - 1]; col = p.x; row = p.y; }
            atomicMax(&lastK[row * Ww + col], k);
        }
        __syncthreads();
        // -- 3x3 max-dilate + decode into padded tile (pad=3 borders zero) --
        for (int i = tid; i < 56 * 109; i += 384) {
            int r = i / 109, c = i % 109;
            int gr = r - 3, gc = c - 3;
            float v = 0.f;
            if (gr >= 0 && gr < Hh && gc >= 0 && gc < Ww) {
                int m = -1;
                #pragma unroll
                for (int dr = -1; dr <= 1; ++dr) {
                    int rr = gr + dr;
                    if (rr < 0 || rr >= Hh) continue;
                    #pragma unroll
                    for (int dc = -1; dc <= 1; ++dc) {
                        int cc = gc + dc;
                        if (cc < 0 || cc >= Ww) continue;
                        m = max(m, lastK[rr * Ww + cc]);
                    }
                }
                v = (m < 0) ? 0.0f : ((lastK[gr * Ww + gc] == m) ? 1.0f : 0.5f);
            }
            pad[i] = v;
        }
        __syncthreads();
        // -- conv1 accumulate for this input channel --
        if (active) {
            const float* wp0 = w1 + (oc0 * 3 + ic) * 49;
            const float* wp1 = w1 + ((oc0 + 1) * 3 + ic) * 49;
            #pragma unroll
            for (int kh = 0; kh < 7; ++kh) {
                const float* lr = pad + (2 * oh + kh) * 109 + 2 * ow0;
                float s[13];
                #pragma unroll
                for (int k = 0; k < 13; ++k) s[k] = lr[k];
                float wa[7], wb_[7];
                #pragma unroll
                for (int k = 0; k < 7; ++k) { wa[k] = wp0[kh * 7 + k]; wb_[k] = wp1[kh * 7 + k]; }
                #pragma unroll
                for (int kw = 0; kw < 7; ++kw)
                    #pragma unroll
                    for (int j = 0; j < 4; ++j) {
                        acc0[j] += s[2 * j + kw] * wa[kw];
                        acc1[j] += s[2 * j + kw] * wb_[kw];
                    }
            }
        }
        __syncthreads();   // pad/lastK reused next ic
    }
    if (active) {
        float bia0 = b1[oc0], bia1 = b1[oc0 + 1];
        #pragma unroll
        for (int j = 0; j < 4; ++j) {
            int ow = ow0 + j;
            if (ow < 51) {
                ctile[(0 * 25 + oh) * 52 + ow] = fmaxf(acc0[j] + bia0, 0.f);
                ctile[(1 * 25 + oh) * 52 + ow] = fmaxf(acc1[j] + bia1, 0.f);
            }
        }
    }
    __syncthreads();
    for (int pu = tid; pu < 600; pu += 384) {    // pool1: 2 oc x 12 x 25
        int oc = pu / 300, rem = pu % 300;
        int ph = rem / 25, pw = rem % 25;
        const float* cp = ctile + (oc * 25 + 2 * ph) * 52 + 2 * pw;
        float m = -INFINITY;
        #pragma unroll
        for (int r = 0; r < 3; ++r)
            #pragma unroll
            for (int c = 0; c < 3; ++c)
                m = fmaxf(m, cp[r * 52 + c]);
        p1[((b * 32 + oc0 + oc) * 12 + ph) * 25 + pw] = m;
    }
}

// ================= K_B: conv2 + pool2 (unchanged, known-good) =================
__global__ void conv2p2_kernel(const float* __restrict__ p1, const float* __restrict__ w2,
                               const float* __restrict__ b2, float* __restrict__ p2) {
    __shared__ float lds[32 * 16 * 29];
    int blk = blockIdx.x;
    int b = blk / 18;
    int tid = threadIdx.x;
    int u = (blk % 18) * 256 + tid;
    for (int i = tid; i < 32 * 16 * 29; i += 256) {
        int ic = i / 464, rem = i % 464;
        int r = rem / 29, c = rem % 29;
        int gr = r - 2, gc = c - 2;
        float v = 0.f;
        if (gr >= 0 && gr < 12 && gc >= 0 && gc < 25)
            v = p1[((b * 32 + ic) * 12 + gr) * 25 + gc];
        lds[i] = v;
    }
    __syncthreads();
    int pw = u % 12, ph = (u / 12) % 6, oc = u / 72;
    float acc[2][2] = {{0.f, 0.f}, {0.f, 0.f}};
    const float* wbase = w2 + oc * 32 * 25;
    const float* lbase = lds + (2 * ph) * 29 + 2 * pw;
    for (int ic = 0; ic < 32; ++ic) {
        float inr[6][6];
        const float* lp = lbase + ic * 464;
        #pragma unroll
        for (int r = 0; r < 6; ++r)
            #pragma unroll
            for (int c = 0; c < 6; ++c)
                inr[r][c] = lp[r * 29 + c];
        const float* wp = wbase + ic * 25;
        float wr[25];
        #pragma unroll
        for (int k = 0; k < 25; ++k) wr[k] = wp[k];
        #pragma unroll
        for (int kh = 0; kh < 5; ++kh)
            #pragma unroll
            for (int kw = 0; kw < 5; ++kw)
                #pragma unroll
                for (int dy = 0; dy < 2; ++dy)
                    #pragma unroll
                    for (int dx = 0; dx < 2; ++dx)
                        acc[dy][dx] += inr[dy + kh][dx + kw] * wr[kh * 5 + kw];
    }
    float bia = b2[oc];
    float m = fmaxf(fmaxf(fmaxf(acc[0][0], acc[0][1]), fmaxf(acc[1][0], acc[1][1])) + bia, 0.f);
    p2[((b * 64 + oc) * 6 + ph) * 12 + pw] = m;
}

// ============ K_C: conv3 + pool3 + per-block feat reduce + head ============
// 160 blocks (16 per b, R4's proven decomposition: u = blk16*144 + tid,
// tid<144 active, 2304 = 16*144 outputs per b). Each block's 144 outputs are
// 8 COMPLETE channels (oc = blk16*8 + tid/18), so each block publishes its 8
// feat values (spatial mean) via agent-scope atomic stores. The 16th-arriving
// block of a b reads all 128 feat via agent-scope atomic loads and runs the
// fc head. p3 never touches global memory.
__global__ __launch_bounds__(256) void conv3p3_head_kernel(
        const float* __restrict__ p2, const float* __restrict__ w3,
        const float* __restrict__ b3, float* __restrict__ featbuf,
        unsigned* __restrict__ cnt,
        const float* __restrict__ wl1, const float* __restrict__ bl1,
        const float* __restrict__ wl2, const float* __restrict__ bl2,
        float* __restrict__ out) {
    __shared__ float smf[64 * 8 * 14];   // staged p2; later reused for feat/h2
    __shared__ float red[144];
    __shared__ unsigned lastflag;
    int blk = blockIdx.x;
    int b = blk / 16, blk16 = blk % 16;
    int tid = threadIdx.x;
    for (int i = tid; i < 64 * 8 * 14; i += 256) {
        int ic = i / 112, rem = i % 112;
        int r = rem / 14, c = rem % 14;
        int gr = r - 1, gc = c - 1;
        float v = 0.f;
        if (gr >= 0 && gr < 6 && gc >= 0 && gc < 12)
            v = p2[((b * 64 + ic) * 6 + gr) * 12 + gc];
        smf[i] = v;
    }
    __syncthreads();
    if (tid < 144) {
        int u = blk16 * 144 + tid;               // < 2304 = 128*18
        int pw = u % 6, ph = (u / 6) % 3, oc = u / 18;
        float acc[2][2] = {{0.f, 0.f}, {0.f, 0.f}};
        const float* wbase = w3 + oc * 64 * 9;
        const float* lbase = smf + (2 * ph) * 14 + 2 * pw;
        for (int ic = 0; ic < 64; ++ic) {
            float inr[4][4];
            const float* lp = lbase + ic * 112;
            #pragma unroll
            for (int r = 0; r < 4; ++r)
                #pragma unroll
                for (int c = 0; c < 4; ++c)
                    inr[r][c] = lp[r * 14 + c];
            const float* wp = wbase + ic * 9;
            float wr[9];
            #pragma unroll
            for (int k = 0; k < 9; ++k) wr[k] = wp[k];
            #pragma unroll
            for (int kh = 0; kh < 3; ++kh)
                #pragma unroll
                for (int kw = 0; kw < 3; ++kw)
                    #pragma unroll
                    for (int dy = 0; dy < 2; ++dy)
                        #pragma unroll
                        for (int dx = 0; dx < 2; ++dx)
                            acc[dy][dx] += inr[dy + kh][dx + kw] * wr[kh * 3 + kw];
        }
        float bia = b3[oc];
        red[tid] = fmaxf(fmaxf(fmaxf(acc[0][0], acc[0][1]),
                               fmaxf(acc[1][0], acc[1][1])) + bia, 0.f);
    }
    __syncthreads();
    if (tid < 8) {   // reduce this block's 8 complete channels -> feat
        float s = 0.0f;
        #pragma unroll
        for (int k = 0; k < 18; ++k) s += red[tid * 18 + k];   // row-major spatial order
        __hip_atomic_store(&featbuf[b * 128 + blk16 * 8 + tid], s * (1.0f / 18.0f),
                           __ATOMIC_RELEASE, __HIP_MEMORY_SCOPE_AGENT);
    }
    // ---- arrival: 16th block of this b runs the head (no spinning) ----
    __syncthreads();
    if (tid == 0) {
        unsigned prev = __hip_atomic_fetch_add(&cnt[b], 1u, __ATOMIC_ACQ_REL,
                                               __HIP_MEMORY_SCOPE_AGENT);
        lastflag = (prev == 15u) ? 1u : 0u;
    }
    __syncthreads();
    if (lastflag) {
        float* feat = smf;        // overlay (p2 stage dead)
        float* h2 = smf + 128;
        int c = tid;
        if (c < 128)
            feat[c] = __hip_atomic_load(&featbuf[b * 128 + c],
                                        __ATOMIC_ACQUIRE, __HIP_MEMORY_SCOPE_AGENT);
        __syncthreads();
        if (c < 128) {
            float a = bl1[c];
            const float4* wr = (const float4*)(wl1 + c * 128);
            #pragma unroll 8
            for (int k4 = 0; k4 < 32; ++k4) {
                float4 w = wr[k4];
                a += feat[4 * k4] * w.x + feat[4 * k4 + 1] * w.y
                   + feat[4 * k4 + 2] * w.z + feat[4 * k4 + 3] * w.w;
            }
            h2[c] = fmaxf(a, 0.0f);
        }
        __syncthreads();
        if (c < 5) {
            float a2 = bl2[c];
            const float4* wr2 = (const float4*)(wl2 + c * 128);
            #pragma unroll 8
            for (int k4 = 0; k4 < 32; ++k4) {
                float4 w = wr2[k4];
                a2 += h2[4 * k4] * w.x + h2[4 * k4 + 1] * w.y
                    + h2[4 * k4 + 2] * w.z + h2[4 * k4 + 3] * w.w;
            }
            out[b * 5 + c] = a2;
        }
    }
}

// ---------------- launch ----------------
extern "C" void kernel_launch(void* const* d_in, const int* in_sizes, int n_in,
                              void* d_out, int out_size, void* d_ws, size_t ws_size,
                              hipStream_t stream) {
    const int*   x   = (const int*)d_in[0];
    const float* w1  = (const float*)d_in[1];
    const float* b1  = (const float*)d_in[2];
    const float* w2  = (const float*)d_in[3];
    const float* b2  = (const float*)d_in[4];
    const float* w3  = (const float*)d_in[5];
    const float* b3  = (const float*)d_in[6];
    const float* wl1 = (const float*)d_in[7];
    const float* bl1 = (const float*)d_in[8];
    const float* wl2 = (const float*)d_in[9];
    const float* bl2 = (const float*)d_in[10];
    float* out = (float*)d_out;

    // workspace:
    //   p1      @ 0      : 384000 B
    //   p2      @ 384000 : 184320 B
    //   featbuf @ 568320 : 5120 B   (10*128 floats, fully rewritten each launch)
    //   cnt     @ 573440 : 40 B     (zeroed by K_A each launch, coherent stores)
    char* ws = (char*)d_ws;
    float*    p1      = (float*)ws;
    float*    p2      = (float*)(ws + 384000);
    float*    featbuf = (float*)(ws + 568320);
    unsigned* cnt     = (unsigned*)(ws + 573440);

    scatter_conv1p1_kernel<<<160, 384, 0, stream>>>(x, w1, b1, p1, cnt);
    conv2p2_kernel<<<180, 256, 0, stream>>>(p1, w2, b2, p2);
    conv3p3_head_kernel<<<160, 256, 0, stream>>>(p2, w3, b3, featbuf, cnt,
                                                 wl1, bl1, wl2, bl2, out);
}

// Round 8
// 91.537 us; speedup vs baseline: 1.7931x; 1.1350x over previous
//
#include <hip/hip_runtime.h>

// ---------------- problem constants ----------------
#define Bb 10
#define Hh 50
#define Ww 101
#define Kk 4096
#define SLICE (Hh*Ww)   // 5050

// conv1: IC=3 OC=32 k7 s2 p3 -> [10,32,25,51]; pool1 k3 s2 -> [10,32,12,25]
// conv2: IC=32 OC=64 k5 s1 p2 -> [10,64,12,25]; pool2 k2 s2 -> [10,64,6,12]
// conv3: IC=64 OC=128 k3 s1 p1 -> [10,128,6,12]; pool3 k2 s2 -> [10,128,3,6]

// ============ K0: scatter + separable 3x3 max-dilate + decode -> grid ============
// 30 blocks (one per (b,c) slice) x 1024 threads. Padded lastKp (border = -1)
// kills all bounds checks; dilation is separable (row-max then col-max):
// 6 LDS reads/cell instead of 9, stride-1, no divergence.
__global__ __launch_bounds__(1024) void scatter_grid_kernel(
        const int* __restrict__ x, float* __restrict__ grid, unsigned* __restrict__ cnt) {
    __shared__ int lastKp[52 * 104];   // [row+1][col+1], border -1
    __shared__ int rowm[52 * 104];     // horizontal 3-max
    int bc = blockIdx.x;
    int tid = threadIdx.x;
    if (bc < Bb && tid == 0)           // zero head counters for K_C (coherent store)
        __hip_atomic_store(&cnt[bc], 0u, __ATOMIC_RELEASE, __HIP_MEMORY_SCOPE_AGENT);
    for (int i = tid; i < 52 * 104; i += 1024) lastKp[i] = -1;
    __syncthreads();
    const int2* xp = (const int2*)(x + bc * Kk * 2);   // (col,row) pairs
    for (int k = tid; k < Kk + 1; k += 1024) {
        int col, row;
        if (k == 0) { col = 50; row = 48; }            // prepended base fill
        else { int2 p = xp[k - 1]; col = p.x; row = p.y; }
        atomicMax(&lastKp[(row + 1) * 104 + (col + 1)], k);
    }
    __syncthreads();
    // row-max pass: rows 0..51 (incl pad rows), padded cols 1..101
    for (int i = tid; i < 52 * 101; i += 1024) {
        int r = i / 101, c = i % 101 + 1;
        const int* lp = &lastKp[r * 104 + c];
        rowm[r * 104 + c] = max(max(lp[-1], lp[0]), lp[1]);
    }
    __syncthreads();
    // col-max + decode: M = 3x3 dilated max; 1.0 iff center holds the max
    float* g = grid + bc * SLICE;
    for (int i = tid; i < SLICE; i += 1024) {
        int r = i / Ww + 1, c = i % Ww + 1;
        int M = max(max(rowm[(r - 1) * 104 + c], rowm[r * 104 + c]),
                    rowm[(r + 1) * 104 + c]);
        g[i] = (M < 0) ? 0.0f : ((lastKp[r * 104 + c] == M) ? 1.0f : 0.5f);
    }
}

// ================= K1: conv1 + pool1 (R3-proven version, global grid in) =================
// 160 blocks (b, ocpair) x 384 threads. Grid slice per ic staged in padded LDS
// [56][109]; conv out (2 oc x 25 x 51) in regs -> LDS -> pooled.
__global__ __launch_bounds__(384) void conv1p1_kernel(
        const float* __restrict__ grid, const float* __restrict__ w1,
        const float* __restrict__ b1, float* __restrict__ p1) {
    __shared__ float lds[56 * 109];
    __shared__ float ctile[2 * 25 * 52];   // stride 52 (pad)
    int blk = blockIdx.x;
    int b = blk / 16, ocpair = blk % 16;
    int oc0 = ocpair * 2;
    int tid = threadIdx.x;
    bool active = tid < 325;               // (oh 25) x (owt 13)
    int oh = tid / 13, owt = tid % 13;
    int ow0 = owt * 4;
    float acc0[4] = {0.f, 0.f, 0.f, 0.f};
    float acc1[4] = {0.f, 0.f, 0.f, 0.f};

    for (int ic = 0; ic < 3; ++ic) {
        for (int i = tid; i < 56 * 109; i += 384) {
            int r = i / 109, c = i % 109;
            int gr = r - 3, gc = c - 3;
            float v = 0.f;
            if (gr >= 0 && gr < Hh && gc >= 0 && gc < Ww)
                v = grid[((b * 3 + ic) * Hh + gr) * Ww + gc];
            lds[i] = v;
        }
        __syncthreads();
        if (active) {
            const float* wp0 = w1 + (oc0 * 3 + ic) * 49;
            const float* wp1 = w1 + ((oc0 + 1) * 3 + ic) * 49;
            #pragma unroll
            for (int kh = 0; kh < 7; ++kh) {
                const float* lr = lds + (2 * oh + kh) * 109 + 2 * ow0;
                float s[13];
                #pragma unroll
                for (int k = 0; k < 13; ++k) s[k] = lr[k];
                float wa[7], wb_[7];
                #pragma unroll
                for (int k = 0; k < 7; ++k) { wa[k] = wp0[kh * 7 + k]; wb_[k] = wp1[kh * 7 + k]; }
                #pragma unroll
                for (int kw = 0; kw < 7; ++kw)
                    #pragma unroll
                    for (int j = 0; j < 4; ++j) {
                        acc0[j] += s[2 * j + kw] * wa[kw];
                        acc1[j] += s[2 * j + kw] * wb_[kw];
                    }
            }
        }
        __syncthreads();
    }
    if (active) {
        float bia0 = b1[oc0], bia1 = b1[oc0 + 1];
        #pragma unroll
        for (int j = 0; j < 4; ++j) {
            int ow = ow0 + j;
            if (ow < 51) {
                ctile[(0 * 25 + oh) * 52 + ow] = fmaxf(acc0[j] + bia0, 0.f);
                ctile[(1 * 25 + oh) * 52 + ow] = fmaxf(acc1[j] + bia1, 0.f);
            }
        }
    }
    __syncthreads();
    for (int pu = tid; pu < 600; pu += 384) {    // pool1: 2 oc x 12 x 25
        int oc = pu / 300, rem = pu % 300;
        int ph = rem / 25, pw = rem % 25;
        const float* cp = ctile + (oc * 25 + 2 * ph) * 52 + 2 * pw;
        float m = -INFINITY;
        #pragma unroll
        for (int r = 0; r < 3; ++r)
            #pragma unroll
            for (int c = 0; c < 3; ++c)
                m = fmaxf(m, cp[r * 52 + c]);
        p1[((b * 32 + oc0 + oc) * 12 + ph) * 25 + pw] = m;
    }
}

// ================= K_B: conv2 + pool2 (unchanged, known-good) =================
__global__ void conv2p2_kernel(const float* __restrict__ p1, const float* __restrict__ w2,
                               const float* __restrict__ b2, float* __restrict__ p2) {
    __shared__ float lds[32 * 16 * 29];
    int blk = blockIdx.x;
    int b = blk / 18;
    int tid = threadIdx.x;
    int u = (blk % 18) * 256 + tid;
    for (int i = tid; i < 32 * 16 * 29; i += 256) {
        int ic = i / 464, rem = i % 464;
        int r = rem / 29, c = rem % 29;
        int gr = r - 2, gc = c - 2;
        float v = 0.f;
        if (gr >= 0 && gr < 12 && gc >= 0 && gc < 25)
            v = p1[((b * 32 + ic) * 12 + gr) * 25 + gc];
        lds[i] = v;
    }
    __syncthreads();
    int pw = u % 12, ph = (u / 12) % 6, oc = u / 72;
    float acc[2][2] = {{0.f, 0.f}, {0.f, 0.f}};
    const float* wbase = w2 + oc * 32 * 25;
    const float* lbase = lds + (2 * ph) * 29 + 2 * pw;
    for (int ic = 0; ic < 32; ++ic) {
        float inr[6][6];
        const float* lp = lbase + ic * 464;
        #pragma unroll
        for (int r = 0; r < 6; ++r)
            #pragma unroll
            for (int c = 0; c < 6; ++c)
                inr[r][c] = lp[r * 29 + c];
        const float* wp = wbase + ic * 25;
        float wr[25];
        #pragma unroll
        for (int k = 0; k < 25; ++k) wr[k] = wp[k];
        #pragma unroll
        for (int kh = 0; kh < 5; ++kh)
            #pragma unroll
            for (int kw = 0; kw < 5; ++kw)
                #pragma unroll
                for (int dy = 0; dy < 2; ++dy)
                    #pragma unroll
                    for (int dx = 0; dx < 2; ++dx)
                        acc[dy][dx] += inr[dy + kh][dx + kw] * wr[kh * 5 + kw];
    }
    float bia = b2[oc];
    float m = fmaxf(fmaxf(fmaxf(acc[0][0], acc[0][1]), fmaxf(acc[1][0], acc[1][1])) + bia, 0.f);
    p2[((b * 64 + oc) * 6 + ph) * 12 + pw] = m;
}

// ============ K_C: conv3 + pool3 + per-block feat reduce + head (unchanged) ============
__global__ __launch_bounds__(256) void conv3p3_head_kernel(
        const float* __restrict__ p2, const float* __restrict__ w3,
        const float* __restrict__ b3, float* __restrict__ featbuf,
        unsigned* __restrict__ cnt,
        const float* __restrict__ wl1, const float* __restrict__ bl1,
        const float* __restrict__ wl2, const float* __restrict__ bl2,
        float* __restrict__ out) {
    __shared__ float smf[64 * 8 * 14];   // staged p2; later reused for feat/h2
    __shared__ float red[144];
    __shared__ unsigned lastflag;
    int blk = blockIdx.x;
    int b = blk / 16, blk16 = blk % 16;
    int tid = threadIdx.x;
    for (int i = tid; i < 64 * 8 * 14; i += 256) {
        int ic = i / 112, rem = i % 112;
        int r = rem / 14, c = rem % 14;
        int gr = r - 1, gc = c - 1;
        float v = 0.f;
        if (gr >= 0 && gr < 6 && gc >= 0 && gc < 12)
            v = p2[((b * 64 + ic) * 6 + gr) * 12 + gc];
        smf[i] = v;
    }
    __syncthreads();
    if (tid < 144) {
        int u = blk16 * 144 + tid;               // < 2304 = 128*18
        int pw = u % 6, ph = (u / 6) % 3, oc = u / 18;
        float acc[2][2] = {{0.f, 0.f}, {0.f, 0.f}};
        const float* wbase = w3 + oc * 64 * 9;
        const float* lbase = smf + (2 * ph) * 14 + 2 * pw;
        for (int ic = 0; ic < 64; ++ic) {
            float inr[4][4];
            const float* lp = lbase + ic * 112;
            #pragma unroll
            for (int r = 0; r < 4; ++r)
                #pragma unroll
                for (int c = 0; c < 4; ++c)
                    inr[r][c] = lp[r * 14 + c];
            const float* wp = wbase + ic * 9;
            float wr[9];
            #pragma unroll
            for (int k = 0; k < 9; ++k) wr[k] = wp[k];
            #pragma unroll
            for (int kh = 0; kh < 3; ++kh)
                #pragma unroll
                for (int kw = 0; kw < 3; ++kw)
                    #pragma unroll
                    for (int dy = 0; dy < 2; ++dy)
                        #pragma unroll
                        for (int dx = 0; dx < 2; ++dx)
                            acc[dy][dx] += inr[dy + kh][dx + kw] * wr[kh * 3 + kw];
        }
        float bia = b3[oc];
        red[tid] = fmaxf(fmaxf(fmaxf(acc[0][0], acc[0][1]),
                               fmaxf(acc[1][0], acc[1][1])) + bia, 0.f);
    }
    __syncthreads();
    if (tid < 8) {   // reduce this block's 8 complete channels -> feat
        float s = 0.0f;
        #pragma unroll
        for (int k = 0; k < 18; ++k) s += red[tid * 18 + k];   // row-major spatial order
        __hip_atomic_store(&featbuf[b * 128 + blk16 * 8 + tid], s * (1.0f / 18.0f),
                           __ATOMIC_RELEASE, __HIP_MEMORY_SCOPE_AGENT);
    }
    // ---- arrival: 16th block of this b runs the head (no spinning) ----
    __syncthreads();
    if (tid == 0) {
        unsigned prev = __hip_atomic_fetch_add(&cnt[b], 1u, __ATOMIC_ACQ_REL,
                                               __HIP_MEMORY_SCOPE_AGENT);
        lastflag = (prev == 15u) ? 1u : 0u;
    }
    __syncthreads();
    if (lastflag) {
        float* feat = smf;        // overlay (p2 stage dead)
        float* h2 = smf + 128;
        int c = tid;
        if (c < 128)
            feat[c] = __hip_atomic_load(&featbuf[b * 128 + c],
                                        __ATOMIC_ACQUIRE, __HIP_MEMORY_SCOPE_AGENT);
        __syncthreads();
        if (c < 128) {
            float a = bl1[c];
            const float4* wr = (const float4*)(wl1 + c * 128);
            #pragma unroll 8
            for (int k4 = 0; k4 < 32; ++k4) {
                float4 w = wr[k4];
                a += feat[4 * k4] * w.x + feat[4 * k4 + 1] * w.y
                   + feat[4 * k4 + 2] * w.z + feat[4 * k4 + 3] * w.w;
            }
            h2[c] = fmaxf(a, 0.0f);
        }
        __syncthreads();
        if (c < 5) {
            float a2 = bl2[c];
            const float4* wr2 = (const float4*)(wl2 + c * 128);
            #pragma unroll 8
            for (int k4 = 0; k4 < 32; ++k4) {
                float4 w = wr2[k4];
                a2 += h2[4 * k4] * w.x + h2[4 * k4 + 1] * w.y
                    + h2[4 * k4 + 2] * w.z + h2[4 * k4 + 3] * w.w;
            }
            out[b * 5 + c] = a2;
        }
    }
}

// ---------------- launch ----------------
extern "C" void kernel_launch(void* const* d_in, const int* in_sizes, int n_in,
                              void* d_out, int out_size, void* d_ws, size_t ws_size,
                              hipStream_t stream) {
    const int*   x   = (const int*)d_in[0];
    const float* w1  = (const float*)d_in[1];
    const float* b1  = (const float*)d_in[2];
    const float* w2  = (const float*)d_in[3];
    const float* b2  = (const float*)d_in[4];
    const float* w3  = (const float*)d_in[5];
    const float* b3  = (const float*)d_in[6];
    const float* wl1 = (const float*)d_in[7];
    const float* bl1 = (const float*)d_in[8];
    const float* wl2 = (const float*)d_in[9];
    const float* bl2 = (const float*)d_in[10];
    float* out = (float*)d_out;

    // workspace:
    //   grid    @ 0       : 606000 B
    //   p1      @ 606000  : 384000 B
    //   p2      @ 990000  : 184320 B
    //   featbuf @ 1174320 : 5120 B
    //   cnt     @ 1179440 : 40 B   (zeroed by K0 each launch, coherent stores)
    char* ws = (char*)d_ws;
    float*    grid    = (float*)ws;
    float*    p1      = (float*)(ws + 606000);
    float*    p2      = (float*)(ws + 990000);
    float*    featbuf = (float*)(ws + 1174320);
    unsigned* cnt     = (unsigned*)(ws + 1179440);

    scatter_grid_kernel<<<30, 1024, 0, stream>>>(x, grid, cnt);
    conv1p1_kernel<<<160, 384, 0, stream>>>(grid, w1, b1, p1);
    conv2p2_kernel<<<180, 256, 0, stream>>>(p1, w2, b2, p2);
    conv3p3_head_kernel<<<160, 256, 0, stream>>>(p2, w3, b3, featbuf, cnt,
                                                 wl1, bl1, wl2, bl2, out);
}